// Round 3
// baseline (572.045 us; speedup 1.0000x reference)
//
#include <hip/hip_runtime.h>

// QuadraticTimeVaryingVF. out[n,h] = b[h] + sum_i o_i*(w_lin[h,i] + sum_{j>=i} wq[h,i,j]*o_j)
//
// R3: (1) prep kernel repacks weights into d_ws as per-(h,wave) chunks of
//     16 rows x 65 floats (lin + zero-padded-to-64 quad row), 64B-aligned,
//     consumption-ordered -> uniform+aligned => s_load_dwordx16, weight rides
//     the SGPR operand of v_fma_f32 (zero per-lane data movement).
//     R1 failed here: 2145-float rows are only 4B-aligned for odd h -> no
//     SMEM merging -> thousands of scalar s_loads + lgkmcnt(0) drains.
// (2) 4-way k-split by row residue -> 4096 waves = 4/SIMD (R1/R2 had 1-2).
// (3) obs staged coalesced via LDS (stride-65 rows: odd -> conflict-free),
//     then lane-private o[64] in VGPRs. Old per-lane dwordx4 loads touched
//     64 cache lines/instr.

#define DOBS   64
#define NH     64
#define WROW   2145
#define NSPLIT 4
#define RPW    (DOBS / NSPLIT)   // 16 rows per wave
#define RLEN   (DOBS + 1)        // 1 lin + 64 padded quad
#define CHUNK  (RPW * RLEN)      // 1040 floats = 4160B (64B multiple)
#define TSTRIDE 65               // LDS obs-tile row stride (odd => conflict-free)

__global__ __launch_bounds__(256) void qvf_prep(
    const float* __restrict__ w, float* __restrict__ wp)
{
    const int h = blockIdx.x >> 2;
    const int s = blockIdx.x & 3;
    const float* __restrict__ src = w + h * WROW;
    float* __restrict__ dst = wp + (size_t)blockIdx.x * CHUNK;
    for (int t = threadIdx.x; t < CHUNK; t += 256) {
        const int r = t / RLEN;
        const int j = t - r * RLEN;          // 0 = lin, 1..64 = quad col j-1
        const int i = NSPLIT * r + s;
        float v;
        if (j == 0) {
            v = src[i];
        } else {
            const int c = j - 1;
            v = (c >= i) ? src[DOBS + i * DOBS - (i * (i - 1)) / 2 + (c - i)]
                         : 0.0f;
        }
        dst[t] = v;
    }
}

__global__ __launch_bounds__(256, 4) void qvf_main(
    const float* __restrict__ obs, const float* __restrict__ wp,
    const float* __restrict__ biases, float* __restrict__ out, int N)
{
    __shared__ float tile[64 * TSTRIDE];
    __shared__ float red[NSPLIT - 1][64];

    const int h    = blockIdx.x & (NH - 1);
    const int tidx = blockIdx.x >> 6;        // n-tile index
    const int lane = threadIdx.x & 63;
    const int s    = threadIdx.x >> 6;       // wave id = k-split id
    const int n0   = tidx * 64;

    // ---- cooperative coalesced stage: obs[n0+nl][h][:] -> tile[nl][:] ----
    {
        const float* __restrict__ src = obs + ((size_t)n0 * NH + h) * DOBS;
        for (int it = 0; it < 4; ++it) {
            const int g  = it * 256 + threadIdx.x;   // float4 slot 0..1023
            const int nl = g >> 4;                   // local path row
            const int c4 = g & 15;                   // float4 within row
            const float4 v = *reinterpret_cast<const float4*>(
                src + (size_t)nl * (NH * DOBS) + c4 * 4);
            float* d = &tile[nl * TSTRIDE + c4 * 4];
            d[0] = v.x; d[1] = v.y; d[2] = v.z; d[3] = v.w;
        }
    }
    __syncthreads();

    // ---- lane-private obs row -> VGPRs (stride-65: conflict-free) ----
    float o[DOBS];
    {
        const float* r = &tile[lane * TSTRIDE];
#pragma unroll
        for (int j = 0; j < DOBS; j += 2) {          // ds_read2_b32-friendly
            o[j]     = r[j];
            o[j + 1] = r[j + 1];
        }
    }

    // ---- uniform FMA stream; weights via s_load_dwordx16 ----
    const float* __restrict__ wc = (const float*)__builtin_assume_aligned(
        wp + (size_t)(h * NSPLIT + s) * CHUNK, 64);

    float acc = 0.f;
#pragma unroll
    for (int rr = 0; rr < RPW; ++rr) {
        const int base = rr * RLEN;
        float t0 = wc[base];                  // linear weight seeds chain 0
        float t1 = 0.f;
#pragma unroll
        for (int j = 0; j < DOBS; j += 2) {
            t0 = fmaf(wc[base + 1 + j], o[j],     t0);
            t1 = fmaf(wc[base + 2 + j], o[j + 1], t1);
        }
        const float oi = (s == 0) ? o[NSPLIT * rr + 0]
                       : (s == 1) ? o[NSPLIT * rr + 1]
                       : (s == 2) ? o[NSPLIT * rr + 2]
                                  : o[NSPLIT * rr + 3];
        acc = fmaf(oi, t0 + t1, acc);
    }

    // ---- k-split reduce + epilogue ----
    if (s > 0) red[s - 1][lane] = acc;
    __syncthreads();
    if (s == 0) {
        const float val = acc + red[0][lane] + red[1][lane] + red[2][lane]
                        + biases[h];
        out[((size_t)n0 + lane) * NH + h] = val;
    }
}

extern "C" void kernel_launch(void* const* d_in, const int* in_sizes, int n_in,
                              void* d_out, int out_size, void* d_ws, size_t ws_size,
                              hipStream_t stream) {
    const float* obs     = (const float*)d_in[0];
    const float* weights = (const float*)d_in[1];
    const float* biases  = (const float*)d_in[2];
    float* out           = (float*)d_out;
    float* wp            = (float*)d_ws;     // 256 * 4160B = 1.04 MB << ws_size

    const int N = in_sizes[0] / (NH * DOBS); // 1024

    qvf_prep<<<dim3(NH * NSPLIT), dim3(256), 0, stream>>>(weights, wp);
    qvf_main<<<dim3((N / 64) * NH), dim3(256), 0, stream>>>(obs, wp, biases, out, N);
}

// Round 4
// 106.314 us; speedup vs baseline: 5.3807x; 5.3807x over previous
//
#include <hip/hip_runtime.h>

// QuadraticTimeVaryingVF. out[n,h] = b[h] + sum_i o_i*(w_lin[h,i] + sum_{j>=i} wq[h,i,j]*o_j)
// obs [N,64,64] f32, weights [64,2145] f32 (last col unused), biases [64] f32.
//
// R4 = R3's weight-repack + 4-way k-split, with R3's spill triggers reverted:
//  * R3 showed VGPR_Count=64 + 1.6 GB HBM scratch traffic: compiler demoted
//    o[64] to scratch (runtime-s select chain + __launch_bounds__(256,4)).
//    -> back to R2's proven pattern: template body<S> (all-constant indices),
//    __launch_bounds__(256) with no min-wave arg.
//  * obs loaded per-lane with dwordx4 (R2-proven, 76 VGPR). All 4 waves of a
//    block issue identical addresses -> L1 serves repeats, HBM stays ~17 MB.
//  * d_ws chunk layout [16 lin][16 x 64-float quad rows]: every row 64B-
//    aligned -> s_load_dwordx16 merging (R3's 65-float rows misaligned).
// Weights ride the SGPR operand of v_fma_f32; per-wave work = 16 rows x 66
// VALU = ~2.1k cyc; 4096 waves = 4/SIMD -> ~3.5 us VALU floor.

#define DOBS   64
#define NH     64
#define WROW   2145
#define NSPLIT 4
#define RPW    (DOBS / NSPLIT)        // 16 rows per wave
#define CHUNK  (RPW + RPW * DOBS)     // 16 lin + 16*64 quad = 1040 floats

__global__ __launch_bounds__(256) void qvf_prep(
    const float* __restrict__ w, float* __restrict__ wp)
{
    const int h = blockIdx.x >> 2;
    const int s = blockIdx.x & 3;
    const float* __restrict__ src = w + h * WROW;
    float* __restrict__ dst = wp + (size_t)blockIdx.x * CHUNK;
    for (int t = threadIdx.x; t < CHUNK; t += 256) {
        float v;
        if (t < RPW) {                         // linear block
            const int i = NSPLIT * t + s;
            v = src[i];
        } else {                               // quad rows, zero-padded below diag
            const int r = (t - RPW) >> 6;
            const int c = (t - RPW) & 63;
            const int i = NSPLIT * r + s;
            v = (c >= i) ? src[DOBS + i * DOBS - (i * (i - 1)) / 2 + (c - i)]
                         : 0.0f;
        }
        dst[t] = v;
    }
}

template <int S>
__device__ __forceinline__ float body(const float* __restrict__ wc,
                                      const float o[DOBS]) {
    float acc = 0.f;
#pragma unroll
    for (int rr = 0; rr < RPW; ++rr) {
        const int qb = RPW + rr * DOBS;        // 64B-aligned quad row
        float t0 = wc[rr];                     // linear weight seeds chain 0
        float t1 = 0.f;
#pragma unroll
        for (int j = 0; j < DOBS; j += 2) {
            t0 = fmaf(wc[qb + j],     o[j],     t0);
            t1 = fmaf(wc[qb + j + 1], o[j + 1], t1);
        }
        acc = fmaf(o[NSPLIT * rr + S], t0 + t1, acc);  // constant index
    }
    return acc;
}

__global__ __launch_bounds__(256) void qvf_main(
    const float* __restrict__ obs, const float* __restrict__ wp,
    const float* __restrict__ biases, float* __restrict__ out, int N)
{
    __shared__ float red[NSPLIT - 1][64];

    const int h    = blockIdx.x & (NH - 1);
    const int tidx = blockIdx.x >> 6;          // n-tile index
    const int lane = threadIdx.x & 63;
    const int s    = threadIdx.x >> 6;         // wave id = k-split id
    const int n    = tidx * 64 + lane;

    // per-lane obs row -> VGPRs (16x dwordx4; identical across the 4 waves -> L1)
    const float* __restrict__ op = obs + (size_t)n * (NH * DOBS) + h * DOBS;
    float o[DOBS];
#pragma unroll
    for (int j = 0; j < DOBS; j += 4) {
        const float4 v = *reinterpret_cast<const float4*>(op + j);
        o[j]     = v.x;
        o[j + 1] = v.y;
        o[j + 2] = v.z;
        o[j + 3] = v.w;
    }

    const float* __restrict__ wc = (const float*)__builtin_assume_aligned(
        wp + (size_t)(h * NSPLIT + s) * CHUNK, 64);

    float acc;
    if      (s == 0) acc = body<0>(wc, o);
    else if (s == 1) acc = body<1>(wc, o);
    else if (s == 2) acc = body<2>(wc, o);
    else             acc = body<3>(wc, o);

    if (s > 0) red[s - 1][lane] = acc;
    __syncthreads();
    if (s == 0) {
        const float val = acc + red[0][lane] + red[1][lane] + red[2][lane]
                        + biases[h];
        out[(size_t)n * NH + h] = val;
    }
}

extern "C" void kernel_launch(void* const* d_in, const int* in_sizes, int n_in,
                              void* d_out, int out_size, void* d_ws, size_t ws_size,
                              hipStream_t stream) {
    const float* obs     = (const float*)d_in[0];
    const float* weights = (const float*)d_in[1];
    const float* biases  = (const float*)d_in[2];
    float* out           = (float*)d_out;
    float* wp            = (float*)d_ws;       // 256 * 4160 B ~= 1.06 MB << ws_size

    const int N = in_sizes[0] / (NH * DOBS);   // 1024

    qvf_prep<<<dim3(NH * NSPLIT), dim3(256), 0, stream>>>(weights, wp);
    qvf_main<<<dim3((N / 64) * NH), dim3(256), 0, stream>>>(obs, wp, biases, out, N);
}

// Round 5
// 76.560 us; speedup vs baseline: 7.4718x; 1.3886x over previous
//
#include <hip/hip_runtime.h>

// QuadraticTimeVaryingVF via MFMA.
// out[n,h] = b[h] + sum_i o_i*(wlin[h,i] + sum_{j>=i} wq[h,i,j]*o_j)
// Reformulated per h:  U[n,i] = sum_{j<96} Waug[h,i,j] * oaug[n,j]
//   Waug[i, j<64] = (j>=i ? wq : 0), Waug[i,64] = wlin_i, else 0
//   oaug[n, j<64] = o[n,j],          oaug[n,64] = 1,      else 0
// then out[n,h] = sum_i o[n,i]*U[n,i] + b[h].
//
// R1/R4 showed the scalar-mem weight path is uncontrollable from HIP
// (SGPR_Count=32 -> single s_load batch in flight -> serialized K$ misses,
// VALUBusy 13%). R5 feeds weights as per-lane MFMA B-fragments from LDS
// (conflict-free ds_read_b128) -- no uniform broadcast anywhere.
// Block = 256 thr (4 waves) per (h, 64-path tile); wave w owns C rows
// w*16..w*16+15; 4 col-tiles x 3 k-steps = 12 mfma_f32_16x16x32_bf16.
// Epilogue reduces sum_i o_i*U_i directly from C-frags with shfl_xor.

#define DOBS 64
#define NH   64
#define WROW 2145
#define KAUG 96      // 64 + 1 (linear) + 31 zero-pad
#define LSTR 104     // LDS row stride (bf16): 208 B = 16B-aligned, 2-way banks max

typedef unsigned short u16;
typedef __attribute__((ext_vector_type(8))) short short8;
typedef __attribute__((ext_vector_type(4))) float floatx4;

__device__ __forceinline__ u16 f2bf(float f) {   // RTNE, inputs are finite
    unsigned u = __float_as_uint(f);
    return (u16)((u + 0x7FFF + ((u >> 16) & 1)) >> 16);
}
__device__ __forceinline__ float bf2f(u16 b) {
    return __uint_as_float(((unsigned)b) << 16);
}

// prep: per h, Waug row-major [64][96] bf16, contiguous.
__global__ __launch_bounds__(256) void qvf_prep(const float* __restrict__ w,
                                                u16* __restrict__ wp) {
    const int h = blockIdx.x;
    const float* __restrict__ src = w + h * WROW;
    u16* __restrict__ dst = wp + (size_t)h * (DOBS * KAUG);
    for (int t = threadIdx.x; t < DOBS * KAUG; t += 256) {
        const int i = t / KAUG;
        const int j = t - i * KAUG;
        float v = 0.f;
        if (j < DOBS) {
            if (j >= i) v = src[DOBS + i * DOBS - (i * (i - 1)) / 2 + (j - i)];
        } else if (j == DOBS) {
            v = src[i];
        }
        dst[t] = f2bf(v);
    }
}

__global__ __launch_bounds__(256) void qvf_main(
    const float* __restrict__ obs, const u16* __restrict__ wp,
    const float* __restrict__ biases, float* __restrict__ out, int N)
{
    __shared__ u16 O16[DOBS * LSTR];   // oaug tiles, [row n][k], stride 104
    __shared__ u16 W16[DOBS * LSTR];   // Waug,      [row i][k], stride 104

    const int h    = blockIdx.x & (NH - 1);
    const int tidx = blockIdx.x >> 6;
    const int lane = threadIdx.x & 63;
    const int wv   = threadIdx.x >> 6;
    const int n0   = tidx * 64;

    // ---- stage obs (fp32 global -> bf16 LDS), coalesced float4 ----
    {
        const float* __restrict__ src = obs + ((size_t)n0 * NH + h) * DOBS;
#pragma unroll
        for (int p = 0; p < 4; ++p) {
            const int g  = p * 256 + threadIdx.x;
            const int r  = g >> 4;            // local path row 0..63
            const int c4 = g & 15;            // float4 within row
            const floatx4 v = *(const floatx4*)(src + (size_t)r * (NH * DOBS) + c4 * 4);
            typedef __attribute__((ext_vector_type(4))) short short4v;
            short4v s;
            s[0] = (short)f2bf(v.x); s[1] = (short)f2bf(v.y);
            s[2] = (short)f2bf(v.z); s[3] = (short)f2bf(v.w);
            *(short4v*)&O16[r * LSTR + c4 * 4] = s;
        }
        // augmented cols 64..95: one 16B segment per thread (64 rows x 4 segs)
        const int r   = threadIdx.x >> 2;
        const int seg = threadIdx.x & 3;
        short8 z = (short8)0;
        if (seg == 0) z[0] = (short)0x3F80;   // bf16 1.0 at k=64
        *(short8*)&O16[r * LSTR + DOBS + seg * 8] = z;
    }
    // ---- stage Waug (bf16 global -> LDS), 16B per thread x 3 passes ----
    {
        const u16* __restrict__ srcw = wp + (size_t)h * (DOBS * KAUG);
#pragma unroll
        for (int p = 0; p < 3; ++p) {
            const int slot = p * 256 + threadIdx.x;   // 768 slots of 8 bf16
            const int i  = slot / 12;
            const int jg = slot - i * 12;
            *(short8*)&W16[i * LSTR + jg * 8] = *(const short8*)(srcw + slot * 8);
        }
    }
    __syncthreads();

    // ---- MFMA: C[m=n_local][i] for rows wv*16..+15, all 64 i ----
    floatx4 acc[4];
#pragma unroll
    for (int ct = 0; ct < 4; ++ct) acc[ct] = (floatx4)0.f;

    const int mrow = wv * 16 + (lane & 15);   // A row (n_local)
    const int q    = lane >> 4;               // quad: k sub-range
#pragma unroll
    for (int ks = 0; ks < 3; ++ks) {
        const short8 a = *(const short8*)&O16[mrow * LSTR + ks * 32 + q * 8];
#pragma unroll
        for (int ct = 0; ct < 4; ++ct) {
            const int i = ct * 16 + (lane & 15);   // B col (i)
            const short8 b = *(const short8*)&W16[i * LSTR + ks * 32 + q * 8];
            acc[ct] = __builtin_amdgcn_mfma_f32_16x16x32_bf16(a, b, acc[ct], 0, 0, 0);
        }
    }

    // ---- epilogue: out[n] = sum_i o[n,i] * U[n,i] + bias ----
    // C/D layout: col = lane&15 (i within tile), row = q*4 + reg (n within strip)
    float P[4] = {0.f, 0.f, 0.f, 0.f};
    const int col = lane & 15;
#pragma unroll
    for (int ct = 0; ct < 4; ++ct) {
#pragma unroll
        for (int r = 0; r < 4; ++r) {
            const int row = wv * 16 + q * 4 + r;               // n_local
            const u16 ov = O16[row * LSTR + ct * 16 + col];    // o (bf16)
            P[r] = fmaf(acc[ct][r], bf2f(ov), P[r]);
        }
    }
#pragma unroll
    for (int msk = 1; msk < 16; msk <<= 1) {
#pragma unroll
        for (int r = 0; r < 4; ++r) P[r] += __shfl_xor(P[r], msk, 64);
    }
    if (col == 0) {
        const float b = biases[h];
#pragma unroll
        for (int r = 0; r < 4; ++r) {
            const int row = wv * 16 + q * 4 + r;
            out[(size_t)(n0 + row) * NH + h] = P[r] + b;
        }
    }
}

extern "C" void kernel_launch(void* const* d_in, const int* in_sizes, int n_in,
                              void* d_out, int out_size, void* d_ws, size_t ws_size,
                              hipStream_t stream) {
    const float* obs     = (const float*)d_in[0];
    const float* weights = (const float*)d_in[1];
    const float* biases  = (const float*)d_in[2];
    float* out           = (float*)d_out;
    u16* wp              = (u16*)d_ws;     // 64*64*96*2 B = 768 KB << ws_size

    const int N = in_sizes[0] / (NH * DOBS);   // 1024

    qvf_prep<<<dim3(NH), dim3(256), 0, stream>>>(weights, wp);
    qvf_main<<<dim3((N / 64) * NH), dim3(256), 0, stream>>>(obs, wp, biases, out, N);
}

// Round 6
// 69.721 us; speedup vs baseline: 8.2047x; 1.0981x over previous
//
#include <hip/hip_runtime.h>

// QuadraticTimeVaryingVF via MFMA, single fused kernel.
// out[n,h] = b[h] + sum_i o_i*(wlin[h,i] + sum_{j>=i} wq[h,i,j]*o_j)
// Per h:  U[n,i] = sum_{j<96} Waug[h,i,j] * oaug[n,j]
//   Waug[i, j<64] = (j>=i ? wq : 0), Waug[i,64] = wlin_i, else 0
//   oaug[n, j<64] = o[n,j],          oaug[n,64] = 1,      else 0
// out[n,h] = sum_i o[n,i]*U[n,i] + b[h], reduced from C-frags via shfl_xor.
//
// R5 lesson: wall = 47us fixed harness overhead (268MB d_ws poison-fill at
// 43us dominates rocprof top-5) + ~30us of prep+main. R6 fuses the Waug
// bf16 conversion into every main block (~24 fp32 reads + packs per thread,
// weights L3-warm from the harness input restore) -> deletes the prep
// dispatch and the d_ws round trip; both load streams issue before the
// single barrier. Weight path stays VECTOR/LDS (R1/R4: scalar-mem path is
// uncontrollable: SGPR_Count=32 -> serialized s_load batches).

#define DOBS 64
#define NH   64
#define WROW 2145
#define KAUG 96      // 64 + 1 (linear) + 31 zero-pad
#define LSTR 104     // LDS row stride in bf16: 208 B, 16B-aligned

typedef unsigned short u16;
typedef __attribute__((ext_vector_type(8))) short short8;
typedef __attribute__((ext_vector_type(4))) short short4v;
typedef __attribute__((ext_vector_type(4))) float floatx4;

__device__ __forceinline__ u16 f2bf(float f) {   // RTNE, finite inputs
    unsigned u = __float_as_uint(f);
    return (u16)((u + 0x7FFF + ((u >> 16) & 1)) >> 16);
}
__device__ __forceinline__ float bf2f(u16 b) {
    return __uint_as_float(((unsigned)b) << 16);
}

__global__ __launch_bounds__(256) void qvf_main(
    const float* __restrict__ obs, const float* __restrict__ weights,
    const float* __restrict__ biases, float* __restrict__ out, int N)
{
    __shared__ u16 O16[DOBS * LSTR];   // oaug tile  [n_local][k]
    __shared__ u16 W16[DOBS * LSTR];   // Waug       [i][k]

    const int h    = blockIdx.x & (NH - 1);
    const int tidx = blockIdx.x >> 6;
    const int lane = threadIdx.x & 63;
    const int wv   = threadIdx.x >> 6;
    const int n0   = tidx * 64;

    // ---- stage Waug: fp32 global -> bf16 LDS, 8-wide packs ----
    // 64 rows x 12 8-col segments = 768 slots, 3 per thread.
    {
        const float* __restrict__ wsrc = weights + h * WROW;
#pragma unroll
        for (int p = 0; p < 3; ++p) {
            const int s   = p * 256 + threadIdx.x;
            const int i   = s / 12;
            const int seg = s - i * 12;
            const int j0  = seg * 8;
            const int qb  = DOBS + i * DOBS - (i * (i - 1)) / 2 - i; // + j
            short8 v8;
#pragma unroll
            for (int e = 0; e < 8; ++e) {
                const int j = j0 + e;
                float v = 0.f;
                if (j < DOBS) {
                    if (j >= i) v = wsrc[qb + j];
                } else if (j == DOBS) {
                    v = wsrc[i];
                }
                v8[e] = (short)f2bf(v);
            }
            *(short8*)&W16[i * LSTR + j0] = v8;
        }
    }

    // ---- stage obs: fp32 global -> bf16 LDS, coalesced float4 ----
    {
        const float* __restrict__ src = obs + ((size_t)n0 * NH + h) * DOBS;
#pragma unroll
        for (int p = 0; p < 4; ++p) {
            const int g  = p * 256 + threadIdx.x;
            const int r  = g >> 4;            // local path row 0..63
            const int c4 = g & 15;            // float4 within row
            const floatx4 v = *(const floatx4*)(src + (size_t)r * (NH * DOBS) + c4 * 4);
            short4v sv;
            sv[0] = (short)f2bf(v.x); sv[1] = (short)f2bf(v.y);
            sv[2] = (short)f2bf(v.z); sv[3] = (short)f2bf(v.w);
            *(short4v*)&O16[r * LSTR + c4 * 4] = sv;
        }
        // augmented cols 64..95: one 16B segment per thread (64 rows x 4 segs)
        const int r   = threadIdx.x >> 2;
        const int seg = threadIdx.x & 3;
        short8 z = (short8)0;
        if (seg == 0) z[0] = (short)0x3F80;   // bf16 1.0 at k=64
        *(short8*)&O16[r * LSTR + DOBS + seg * 8] = z;
    }
    __syncthreads();

    // ---- MFMA: C[m=n_local][i], wave wv owns rows wv*16..+15 ----
    floatx4 acc[4];
#pragma unroll
    for (int ct = 0; ct < 4; ++ct) acc[ct] = (floatx4)0.f;

    const int mrow = wv * 16 + (lane & 15);
    const int q    = lane >> 4;
#pragma unroll
    for (int ks = 0; ks < 3; ++ks) {
        const short8 a = *(const short8*)&O16[mrow * LSTR + ks * 32 + q * 8];
#pragma unroll
        for (int ct = 0; ct < 4; ++ct) {
            const int i = ct * 16 + (lane & 15);
            const short8 b = *(const short8*)&W16[i * LSTR + ks * 32 + q * 8];
            acc[ct] = __builtin_amdgcn_mfma_f32_16x16x32_bf16(a, b, acc[ct], 0, 0, 0);
        }
    }

    // ---- epilogue: out[n] = sum_i o[n,i]*U[n,i] + bias ----
    // C/D layout: col = lane&15 (i), row = q*4 + reg (n within 16-strip)
    float P[4] = {0.f, 0.f, 0.f, 0.f};
    const int col = lane & 15;
#pragma unroll
    for (int ct = 0; ct < 4; ++ct) {
#pragma unroll
        for (int r = 0; r < 4; ++r) {
            const int row = wv * 16 + q * 4 + r;
            const u16 ov = O16[row * LSTR + ct * 16 + col];
            P[r] = fmaf(acc[ct][r], bf2f(ov), P[r]);
        }
    }
#pragma unroll
    for (int msk = 1; msk < 16; msk <<= 1) {
#pragma unroll
        for (int r = 0; r < 4; ++r) P[r] += __shfl_xor(P[r], msk, 64);
    }
    if (col == 0) {
        const float b = biases[h];
#pragma unroll
        for (int r = 0; r < 4; ++r) {
            const int row = wv * 16 + q * 4 + r;
            out[(size_t)(n0 + row) * NH + h] = P[r] + b;
        }
    }
}

extern "C" void kernel_launch(void* const* d_in, const int* in_sizes, int n_in,
                              void* d_out, int out_size, void* d_ws, size_t ws_size,
                              hipStream_t stream) {
    const float* obs     = (const float*)d_in[0];
    const float* weights = (const float*)d_in[1];
    const float* biases  = (const float*)d_in[2];
    float* out           = (float*)d_out;

    const int N = in_sizes[0] / (NH * DOBS);   // 1024
    qvf_main<<<dim3((N / 64) * NH), dim3(256), 0, stream>>>(obs, weights, biases, out, N);
}

// Round 7
// 68.327 us; speedup vs baseline: 8.3722x; 1.0204x over previous
//
#include <hip/hip_runtime.h>

// QuadraticTimeVaryingVF via MFMA, single fused kernel (R7).
// out[n,h] = b[h] + sum_i o_i*(wlin[h,i] + sum_{j>=i} wq[h,i,j]*o_j)
// Per h: U[n,i] = wlin[i] + sum_{k<64} Wq[i,k]*o[n,k]  (K=64 exactly:
//   wlin seeds the MFMA accumulator -- C/D layout col=i is row-invariant)
// out[n,h] = sum_i o[n,i]*U[n,i] + b[h], reduced from C-frags via shfl_xor.
//
// R6 post-mortem: wall = ~52us harness floor (268MB d_ws poison 44us +
// restores) + ~18us main. Main's cost = front-end: 24 scattered weight
// dwords/thread (~32 cache lines per wave-instr) + K=96 with 1/3 zero-pad.
// R7: (1) K=64 via fp32 wlin C-init (kills 4 MFMAs + aug staging),
// (2) coalesced triangle read (8 lane-consecutive dwords/thread) + LDS
// scatter via closed-form inverse-triangle (exact fp32 sqrt + fixup),
// (3) LSTR 104->72: LDS 18.7KB -> 8 blocks/CU.

#define DOBS 64
#define NH   64
#define WROW 2145
#define NQUAD 2080            // upper-tri count
#define LSTR 72               // LDS row stride (bf16): 144 B, 16B-aligned

typedef unsigned short u16;
typedef __attribute__((ext_vector_type(8))) short short8;
typedef __attribute__((ext_vector_type(4))) short short4v;
typedef __attribute__((ext_vector_type(4))) float floatx4;

__device__ __forceinline__ u16 f2bf(float f) {   // RTNE, finite inputs
    unsigned u = __float_as_uint(f);
    return (u16)((u + 0x7FFF + ((u >> 16) & 1)) >> 16);
}
__device__ __forceinline__ float bf2f(u16 b) {
    return __uint_as_float(((unsigned)b) << 16);
}
__device__ __forceinline__ int tri_start(int i) {  // quad-region offset of row i
    return (i * (129 - i)) >> 1;                   // i*64 - i*(i-1)/2
}

__global__ __launch_bounds__(256) void qvf_main(
    const float* __restrict__ obs, const float* __restrict__ weights,
    const float* __restrict__ biases, float* __restrict__ out, int N)
{
    __shared__ u16 O16[DOBS * LSTR];   // o tile   [n_local][k] bf16
    __shared__ u16 W16[DOBS * LSTR];   // Wq       [i][k]       bf16
    __shared__ float LW[DOBS];         // wlin     fp32

    const int h    = blockIdx.x & (NH - 1);
    const int tidx = blockIdx.x >> 6;
    const int lane = threadIdx.x & 63;
    const int wv   = threadIdx.x >> 6;
    const int n0   = tidx * 64;

    const float* __restrict__ wsrc = weights + h * WROW;

    // ---- phase 0: issue coalesced quad-weight loads into registers ----
    float wq[8];
#pragma unroll
    for (int p = 0; p < 8; ++p)
        wq[p] = wsrc[DOBS + p * 256 + threadIdx.x];          // 2048 elems
    float wq8 = 0.f;
    if (threadIdx.x < NQUAD - 2048)                          // last 32
        wq8 = wsrc[DOBS + 2048 + threadIdx.x];

    // linear weights -> LDS fp32
    if (threadIdx.x < DOBS) LW[threadIdx.x] = wsrc[threadIdx.x];

    // zero W16 (covers below-diagonal; 4608 shorts = 576 short8 slots)
    {
        const short8 z = (short8)0;
        *(short8*)&W16[threadIdx.x * 8]         = z;
        *(short8*)&W16[(256 + threadIdx.x) * 8] = z;
        if (threadIdx.x < 64) *(short8*)&W16[(512 + threadIdx.x) * 8] = z;
    }

    // obs staging: fp32 global -> bf16 LDS, coalesced float4
    {
        const float* __restrict__ src = obs + ((size_t)n0 * NH + h) * DOBS;
#pragma unroll
        for (int p = 0; p < 4; ++p) {
            const int g  = p * 256 + threadIdx.x;
            const int r  = g >> 4;            // local path row 0..63
            const int c4 = g & 15;            // float4 within row
            const floatx4 v = *(const floatx4*)(src + (size_t)r * (NH * DOBS) + c4 * 4);
            short4v sv;
            sv[0] = (short)f2bf(v.x); sv[1] = (short)f2bf(v.y);
            sv[2] = (short)f2bf(v.z); sv[3] = (short)f2bf(v.w);
            *(short4v*)&O16[r * LSTR + c4 * 4] = sv;
        }
    }
    __syncthreads();   // zeros visible before scatter overwrites diagonal+

    // ---- phase 1: scatter quad weights into W16[i][j] ----
    // linear q -> row i = floor((129 - sqrt(129^2 - 8q))/2), j = i + q - S(i)
#pragma unroll
    for (int p = 0; p < 9; ++p) {
        const int q = p * 256 + threadIdx.x;
        if (p == 8 && q >= NQUAD) break;
        const float v = (p < 8) ? wq[p] : wq8;
        const int   t = 16641 - 8 * q;                 // exact in fp32 range
        int i = (int)((129.0f - __builtin_sqrtf((float)t)) * 0.5f);
        i = (i < 0) ? 0 : ((i > 63) ? 63 : i);
        if (q < tri_start(i)) --i;                     // +/-1 fixup
        if (q >= tri_start(i + 1)) ++i;
        const int j = i + (q - tri_start(i));
        W16[i * LSTR + j] = f2bf(v);
    }
    __syncthreads();

    // ---- MFMA: C[m=n_local][i], acc seeded with fp32 wlin[i] ----
    const int col = lane & 15;
    const int qq  = lane >> 4;
    floatx4 acc[4];
#pragma unroll
    for (int ct = 0; ct < 4; ++ct) {
        const float wl = LW[ct * 16 + col];
        acc[ct][0] = wl; acc[ct][1] = wl; acc[ct][2] = wl; acc[ct][3] = wl;
    }

    const int mrow = wv * 16 + col;
#pragma unroll
    for (int ks = 0; ks < 2; ++ks) {
        const short8 a = *(const short8*)&O16[mrow * LSTR + ks * 32 + qq * 8];
#pragma unroll
        for (int ct = 0; ct < 4; ++ct) {
            const int i = ct * 16 + col;
            const short8 b = *(const short8*)&W16[i * LSTR + ks * 32 + qq * 8];
            acc[ct] = __builtin_amdgcn_mfma_f32_16x16x32_bf16(a, b, acc[ct], 0, 0, 0);
        }
    }

    // ---- epilogue: out[n] = sum_i o[n,i]*U[n,i] + bias ----
    // C/D layout: col = lane&15 (i), row = qq*4 + reg (n within 16-strip)
    float P[4] = {0.f, 0.f, 0.f, 0.f};
#pragma unroll
    for (int ct = 0; ct < 4; ++ct) {
#pragma unroll
        for (int r = 0; r < 4; ++r) {
            const int row = wv * 16 + qq * 4 + r;
            const u16 ov = O16[row * LSTR + ct * 16 + col];
            P[r] = fmaf(acc[ct][r], bf2f(ov), P[r]);
        }
    }
#pragma unroll
    for (int msk = 1; msk < 16; msk <<= 1) {
#pragma unroll
        for (int r = 0; r < 4; ++r) P[r] += __shfl_xor(P[r], msk, 64);
    }
    if (col == 0) {
        const float b = biases[h];
#pragma unroll
        for (int r = 0; r < 4; ++r) {
            const int row = wv * 16 + qq * 4 + r;
            out[(size_t)(n0 + row) * NH + h] = P[r] + b;
        }
    }
}

extern "C" void kernel_launch(void* const* d_in, const int* in_sizes, int n_in,
                              void* d_out, int out_size, void* d_ws, size_t ws_size,
                              hipStream_t stream) {
    const float* obs     = (const float*)d_in[0];
    const float* weights = (const float*)d_in[1];
    const float* biases  = (const float*)d_in[2];
    float* out           = (float*)d_out;

    const int N = in_sizes[0] / (NH * DOBS);   // 1024
    qvf_main<<<dim3((N / 64) * NH), dim3(256), 0, stream>>>(obs, weights, biases, out, N);
}